// Round 2
// baseline (198.626 us; speedup 1.0000x reference)
//
#include <hip/hip_runtime.h>

// Segment-mean pooling: feats [N, 256] fp32, segment_ids [N] sorted int32,
// out [S, 256] fp32. S = out_size / 256. Fused: each block binary-searches
// its own segment bounds (no separate starts kernel, no workspace).

#define DCOLS 256
#define D4    64   // DCOLS / 4 float4s per row

__global__ __launch_bounds__(256) void seg_mean_fused(
        const float* __restrict__ feats,
        const int* __restrict__ ids,
        int N,
        float* __restrict__ out) {
    const int s = blockIdx.x;

    // Lanes 0,1 of wave 0: lower_bound(ids, s) and lower_bound(ids, s+1).
    __shared__ int bounds[2];
    if (threadIdx.x < 2) {
        const int target = s + (int)threadIdx.x;
        int lo = 0, hi = N;
        while (lo < hi) {
            int mid = (lo + hi) >> 1;
            if (ids[mid] < target) lo = mid + 1;
            else hi = mid;
        }
        bounds[threadIdx.x] = lo;
    }
    __syncthreads();

    const int start = bounds[0];
    const int end   = bounds[1];
    const int count = end - start;

    const int cg = threadIdx.x & 63;  // column group: one float4
    const int rg = threadIdx.x >> 6;  // row group: 4 waves stride rows by 4

    const float4* f4 = reinterpret_cast<const float4*>(feats);

    // 2-way unroll, dual accumulators -> >=2 outstanding loads per lane.
    float4 acc0 = make_float4(0.f, 0.f, 0.f, 0.f);
    float4 acc1 = make_float4(0.f, 0.f, 0.f, 0.f);
    int r = start + rg;
    for (; r + 4 < end; r += 8) {
        float4 v0 = f4[(size_t)r * D4 + cg];
        float4 v1 = f4[(size_t)(r + 4) * D4 + cg];
        acc0.x += v0.x; acc0.y += v0.y; acc0.z += v0.z; acc0.w += v0.w;
        acc1.x += v1.x; acc1.y += v1.y; acc1.z += v1.z; acc1.w += v1.w;
    }
    if (r < end) {
        float4 v = f4[(size_t)r * D4 + cg];
        acc0.x += v.x; acc0.y += v.y; acc0.z += v.z; acc0.w += v.w;
    }
    acc0.x += acc1.x; acc0.y += acc1.y; acc0.z += acc1.z; acc0.w += acc1.w;

    __shared__ float4 buf[256];
    buf[threadIdx.x] = acc0;
    __syncthreads();

    if (threadIdx.x < 64) {
        float4 a = buf[threadIdx.x];
        float4 b = buf[threadIdx.x + 64];
        float4 c = buf[threadIdx.x + 128];
        float4 d = buf[threadIdx.x + 192];
        float cnt = (float)(count > 0 ? count : 1);
        float4 o;
        o.x = (a.x + b.x + c.x + d.x) / cnt;
        o.y = (a.y + b.y + c.y + d.y) / cnt;
        o.z = (a.z + b.z + c.z + d.z) / cnt;
        o.w = (a.w + b.w + c.w + d.w) / cnt;
        reinterpret_cast<float4*>(out)[(size_t)s * D4 + threadIdx.x] = o;
    }
}

extern "C" void kernel_launch(void* const* d_in, const int* in_sizes, int n_in,
                              void* d_out, int out_size, void* d_ws, size_t ws_size,
                              hipStream_t stream) {
    const float* feats = (const float*)d_in[0];
    const int*   ids   = (const int*)d_in[1];
    const int S = out_size / DCOLS;
    const int N = in_sizes[0] / DCOLS;

    seg_mean_fused<<<S, 256, 0, stream>>>(feats, ids, N, (float*)d_out);
}